// Round 1
// baseline (309.251 us; speedup 1.0000x reference)
//
#include <hip/hip_runtime.h>

// Fully-fused PINN-LISTA kernel: one 64-thread block (1 wave) owns 16 samples.
// Phase 1: 100-step LNN scan with f16 MFMA 16x16x16 (fp32 accum), h state in
//          C-fragment registers, per-step LDS round-trip in A-frag-native layout.
// Phase 2: x = h@Wx0^T + bx0 (MFMA).
// Phase 3: 8 ISTA iterations, z = y@We[k]^T + x@Wr[k]^T + be[k] (MFMA, We/Wr
//          streamed from L2), soft-threshold.
// Phase 4: head GEMV via LDS, write power + x.

#define NB 32768
#define WIN 100
#define HH 64
#define AA 64
#define KITER 8
#define NAPPC 4
#define DTC 0.1f
#define LNEPS 1e-5f

typedef _Float16 f16x4 __attribute__((ext_vector_type(4)));
typedef float f32x4 __attribute__((ext_vector_type(4)));

__device__ __forceinline__ float exp2_fast(float x) { return __builtin_amdgcn_exp2f(x); }
__device__ __forceinline__ float rcp_fast(float x) { return __builtin_amdgcn_rcpf(x); }
__device__ __forceinline__ float rsq_fast(float x) { return __builtin_amdgcn_rsqf(x); }
__device__ __forceinline__ float log2_fast(float x) { return __builtin_amdgcn_logf(x); }

__device__ __forceinline__ float tanh_fast(float x) {
  // tanh(x) = (e^{2x}-1)/(e^{2x}+1); exp2-based, saturates cleanly both sides
  float e = exp2_fast(x * 2.8853900817779268f);  // 2*log2(e)
  return (e - 1.0f) * rcp_fast(e + 1.0f);
}
__device__ __forceinline__ float softplus_fast(float x) {
  float ax = fabsf(x);
  float e = exp2_fast(-ax * 1.4426950408889634f);
  return fmaxf(x, 0.0f) + log2_fast(1.0f + e) * 0.6931471805599453f;
}

__global__ __launch_bounds__(64, 2) void pinn_fused(
    const float* __restrict__ y, const float* __restrict__ w_in,
    const float* __restrict__ b_in, const float* __restrict__ tau_param,
    const float* __restrict__ W_rec, const float* __restrict__ ln_w,
    const float* __restrict__ ln_b, const float* __restrict__ Wx0,
    const float* __restrict__ bx0, const float* __restrict__ We,
    const float* __restrict__ be, const float* __restrict__ Wr,
    const float* __restrict__ thr, const float* __restrict__ head_W,
    const float* __restrict__ head_b, float* __restrict__ out) {
  __shared__ float ybuf[16][104];                    // y tile fp32 (also reused for head)
  __shared__ __align__(16) _Float16 hbuf[16][17][4]; // A-frag-native: [k>>2][sample(pad)][k&3]

  const int l = threadIdx.x;
  const int c = l & 15;   // C col / A row (sample for A-frags)
  const int g = l >> 4;   // k-group / reg-group
  const int s0 = blockIdx.x * 16;

  // ---- stage y tile (coalesced-ish 32B chunks) ----
  {
    const int r = l >> 3, t0 = l & 7;
#pragma unroll
    for (int ss = 0; ss < 2; ++ss) {
      const int s = r + ss * 8;
      for (int t = t0; t < WIN; t += 8) ybuf[s][t] = y[(s0 + s) * WIN + t];
    }
  }

  // ---- per-H constants (H index = 16*nt + c, matches C-layout column) ----
  float w_in_r[4], b_in_r[4], ln_w_r[4], ln_b_r[4], decay_r[4];
#pragma unroll
  for (int nt = 0; nt < 4; ++nt) {
    const int hh = nt * 16 + c;
    w_in_r[nt] = w_in[hh];
    b_in_r[nt] = b_in[hh];
    ln_w_r[nt] = ln_w[hh];
    ln_b_r[nt] = ln_b[hh];
    decay_r[nt] = 1.0f - DTC / softplus_fast(tau_param[hh]);
  }

  // ---- W_rec B-fragments: B[k][n] = W_rec[k*H + n], k = kt*16 + g*4 + j ----
  f16x4 wrec[4][4];
#pragma unroll
  for (int kt = 0; kt < 4; ++kt)
#pragma unroll
    for (int nt = 0; nt < 4; ++nt)
#pragma unroll
      for (int j = 0; j < 4; ++j)
        wrec[kt][nt][j] = (_Float16)W_rec[(kt * 16 + g * 4 + j) * HH + nt * 16 + c];

  // h state in C-fragment layout: hc[nt][reg] = h[sample 4g+reg][H 16nt+c]
  f32x4 hc[4] = {};
  const float inv64 = 1.0f / 64.0f;

  // ================= Phase 1: 100-step scan =================
  for (int t = 0; t < WIN; ++t) {
    __syncthreads();
#pragma unroll
    for (int nt = 0; nt < 4; ++nt) {
      const int chunk = nt * 4 + (c >> 2), pos = c & 3;
#pragma unroll
      for (int reg = 0; reg < 4; ++reg)
        hbuf[chunk][g * 4 + reg][pos] = (_Float16)hc[nt][reg];
    }
    __syncthreads();
    f16x4 afr[4];
#pragma unroll
    for (int kt = 0; kt < 4; ++kt) afr[kt] = *(const f16x4*)&hbuf[kt * 4 + g][c][0];

    f32x4 acc[4];
#pragma unroll
    for (int nt = 0; nt < 4; ++nt) {
      f32x4 a = {0.f, 0.f, 0.f, 0.f};
#pragma unroll
      for (int kt = 0; kt < 4; ++kt)
        a = __builtin_amdgcn_mfma_f32_16x16x16f16(afr[kt], wrec[kt][nt], a, 0, 0, 0);
      acc[nt] = a;
    }

    float xt[4];
#pragma unroll
    for (int reg = 0; reg < 4; ++reg) xt[reg] = ybuf[g * 4 + reg][t];

#pragma unroll
    for (int reg = 0; reg < 4; ++reg) {
      float pr[4];
#pragma unroll
      for (int nt = 0; nt < 4; ++nt)
        pr[nt] = acc[nt][reg] + fmaf(xt[reg], w_in_r[nt], b_in_r[nt]);
      // LN over 64 H: local (4 nt) + 16-lane shfl reduce
      float sum = (pr[0] + pr[1]) + (pr[2] + pr[3]);
      sum += __shfl_xor(sum, 1);
      sum += __shfl_xor(sum, 2);
      sum += __shfl_xor(sum, 4);
      sum += __shfl_xor(sum, 8);
      const float mean = sum * inv64;
      float d[4];
#pragma unroll
      for (int nt = 0; nt < 4; ++nt) d[nt] = pr[nt] - mean;
      float q = (d[0] * d[0] + d[1] * d[1]) + (d[2] * d[2] + d[3] * d[3]);
      q += __shfl_xor(q, 1);
      q += __shfl_xor(q, 2);
      q += __shfl_xor(q, 4);
      q += __shfl_xor(q, 8);
      const float rstd = rsq_fast(fmaf(q, inv64, LNEPS));
#pragma unroll
      for (int nt = 0; nt < 4; ++nt) {
        const float f = tanh_fast(fmaf(d[nt] * rstd, ln_w_r[nt], ln_b_r[nt]));
        hc[nt][reg] = fminf(10.0f, fmaxf(-10.0f, fmaf(hc[nt][reg], decay_r[nt], DTC * f)));
      }
    }
  }

  // ================= Phase 2: x = h @ Wx0^T + bx0 =================
  __syncthreads();
#pragma unroll
  for (int nt = 0; nt < 4; ++nt) {
    const int chunk = nt * 4 + (c >> 2), pos = c & 3;
#pragma unroll
    for (int reg = 0; reg < 4; ++reg)
      hbuf[chunk][g * 4 + reg][pos] = (_Float16)hc[nt][reg];
  }
  __syncthreads();
  f32x4 xc[4];
  {
    f16x4 afr[4];
#pragma unroll
    for (int kt = 0; kt < 4; ++kt) afr[kt] = *(const f16x4*)&hbuf[kt * 4 + g][c][0];
#pragma unroll
    for (int nt = 0; nt < 4; ++nt) {
      f32x4 a = {0.f, 0.f, 0.f, 0.f};
#pragma unroll
      for (int kt = 0; kt < 4; ++kt) {
        f16x4 wf;
#pragma unroll
        for (int j = 0; j < 4; ++j)
          wf[j] = (_Float16)Wx0[(nt * 16 + c) * HH + kt * 16 + g * 4 + j];
        a = __builtin_amdgcn_mfma_f32_16x16x16f16(afr[kt], wf, a, 0, 0, 0);
      }
      const float bx = bx0[nt * 16 + c];
#pragma unroll
      for (int reg = 0; reg < 4; ++reg) a[reg] += bx;
      xc[nt] = a;
    }
  }

  // ---- y A-fragments for ISTA (K padded 100 -> 112, zeros) ----
  f16x4 yfr[7];
#pragma unroll
  for (int kt = 0; kt < 7; ++kt)
#pragma unroll
    for (int j = 0; j < 4; ++j) {
      const int t = kt * 16 + g * 4 + j;
      yfr[kt][j] = (t < WIN) ? (_Float16)ybuf[c][t] : (_Float16)0.0f;
    }

  // ================= Phase 3: ISTA iterations =================
  for (int k = 0; k < KITER; ++k) {
    __syncthreads();
#pragma unroll
    for (int nt = 0; nt < 4; ++nt) {
      const int chunk = nt * 4 + (c >> 2), pos = c & 3;
#pragma unroll
      for (int reg = 0; reg < 4; ++reg)
        hbuf[chunk][g * 4 + reg][pos] = (_Float16)xc[nt][reg];
    }
    __syncthreads();
    f16x4 xafr[4];
#pragma unroll
    for (int kt = 0; kt < 4; ++kt) xafr[kt] = *(const f16x4*)&hbuf[kt * 4 + g][c][0];

#pragma unroll
    for (int nt = 0; nt < 4; ++nt) {
      const int arow = nt * 16 + c;
      f32x4 a = {0.f, 0.f, 0.f, 0.f};
#pragma unroll
      for (int kt = 0; kt < 7; ++kt) {
        f16x4 wf;
#pragma unroll
        for (int j = 0; j < 4; ++j) {
          const int t = kt * 16 + g * 4 + j;
          wf[j] = (t < WIN) ? (_Float16)We[(k * AA + arow) * WIN + t] : (_Float16)0.0f;
        }
        a = __builtin_amdgcn_mfma_f32_16x16x16f16(yfr[kt], wf, a, 0, 0, 0);
      }
#pragma unroll
      for (int kt = 0; kt < 4; ++kt) {
        f16x4 wf;
#pragma unroll
        for (int j = 0; j < 4; ++j)
          wf[j] = (_Float16)Wr[(k * AA + arow) * AA + kt * 16 + g * 4 + j];
        a = __builtin_amdgcn_mfma_f32_16x16x16f16(xafr[kt], wf, a, 0, 0, 0);
      }
      const float bev = be[k * AA + arow];
      const float lam = softplus_fast(thr[k * AA + arow]);
#pragma unroll
      for (int reg = 0; reg < 4; ++reg) {
        const float z = a[reg] + bev;
        const float v = fmaxf(fabsf(z) - lam, 0.0f);
        xc[nt][reg] = copysignf(v, z);
      }
    }
  }

  // ================= Phase 4: outputs =================
  float* __restrict__ outp = out;              // power (B, 4)
  float* __restrict__ outx = out + NB * NAPPC; // x (B, 64)
#pragma unroll
  for (int nt = 0; nt < 4; ++nt)
#pragma unroll
    for (int reg = 0; reg < 4; ++reg)
      outx[(s0 + g * 4 + reg) * AA + nt * 16 + c] = xc[nt][reg];

  __syncthreads();
#pragma unroll
  for (int nt = 0; nt < 4; ++nt)
#pragma unroll
    for (int reg = 0; reg < 4; ++reg)
      ybuf[g * 4 + reg][nt * 16 + c] = xc[nt][reg];
  __syncthreads();
  {
    // lane -> (p = g, s = c); 4 heads x 16 samples = 64 lanes
    float accp = head_b[g];
#pragma unroll 8
    for (int a = 0; a < AA; ++a) accp = fmaf(ybuf[c][a], head_W[g * AA + a], accp);
    outp[(s0 + c) * NAPPC + g] = accp;
  }
}

extern "C" void kernel_launch(void* const* d_in, const int* in_sizes, int n_in,
                              void* d_out, int out_size, void* d_ws, size_t ws_size,
                              hipStream_t stream) {
  const float* y         = (const float*)d_in[0];
  const float* w_in      = (const float*)d_in[1];
  const float* b_in      = (const float*)d_in[2];
  const float* tau_param = (const float*)d_in[3];
  const float* W_rec     = (const float*)d_in[4];
  const float* ln_w      = (const float*)d_in[5];
  const float* ln_b      = (const float*)d_in[6];
  const float* Wx0       = (const float*)d_in[7];
  const float* bx0       = (const float*)d_in[8];
  const float* We        = (const float*)d_in[9];
  const float* be        = (const float*)d_in[10];
  const float* Wr        = (const float*)d_in[11];
  const float* thr       = (const float*)d_in[12];
  const float* head_W    = (const float*)d_in[13];
  const float* head_b    = (const float*)d_in[14];

  pinn_fused<<<dim3(NB / 16), dim3(64), 0, stream>>>(
      y, w_in, b_in, tau_param, W_rec, ln_w, ln_b, Wx0, bx0, We, be, Wr, thr,
      head_W, head_b, (float*)d_out);
}

// Round 2
// 170.379 us; speedup vs baseline: 1.8151x; 1.8151x over previous
//
#include <hip/hip_runtime.h>

// Fully-fused PINN-LISTA kernel, transposed-MFMA formulation.
// One 64-thread block (1 wave) owns 16 samples (columns of all products).
// Computing pre^T = W_rec^T @ h^T makes the MFMA C-fragment layout
// (col=sample=l&15, row=4*(l>>4)+reg) IDENTICAL to the B-fragment layout
// needed by the next step -> no LDS round-trip, no barriers in the scan.
// LayerNorm axis (H) = 16 in-lane elements x 4 lane-groups -> 2 shfls.

#define NB 32768
#define WIN 100
#define HH 64
#define AA 64
#define KITER 8
#define NAPPC 4
#define DTC 0.1f
#define LNEPS 1e-5f

typedef _Float16 f16x4 __attribute__((ext_vector_type(4)));
typedef float f32x4 __attribute__((ext_vector_type(4)));

__device__ __forceinline__ float exp2_fast(float x) { return __builtin_amdgcn_exp2f(x); }
__device__ __forceinline__ float rcp_fast(float x) { return __builtin_amdgcn_rcpf(x); }
__device__ __forceinline__ float rsq_fast(float x) { return __builtin_amdgcn_rsqf(x); }
__device__ __forceinline__ float log2_fast(float x) { return __builtin_amdgcn_logf(x); }

__device__ __forceinline__ float tanh_fast(float x) {
  // tanh(x) = (e^{2x}-1)/(e^{2x}+1); clamp hi side so inf*0 NaN can't form
  float a = fminf(x * 2.8853900817779268f, 80.0f);  // 2*log2(e)
  float e = exp2_fast(a);
  return (e - 1.0f) * rcp_fast(e + 1.0f);
}
__device__ __forceinline__ float softplus_fast(float x) {
  float ax = fabsf(x);
  float e = exp2_fast(-ax * 1.4426950408889634f);
  return fmaxf(x, 0.0f) + log2_fast(1.0f + e) * 0.6931471805599453f;
}

__global__ __launch_bounds__(64, 2) void pinn_fused(
    const float* __restrict__ y, const float* __restrict__ w_in,
    const float* __restrict__ b_in, const float* __restrict__ tau_param,
    const float* __restrict__ W_rec, const float* __restrict__ ln_w,
    const float* __restrict__ ln_b, const float* __restrict__ Wx0,
    const float* __restrict__ bx0, const float* __restrict__ We,
    const float* __restrict__ be, const float* __restrict__ Wr,
    const float* __restrict__ thr, const float* __restrict__ head_W,
    const float* __restrict__ head_b, float* __restrict__ out) {
  __shared__ float ybuf[16][101];  // stride 101: c*101 mod 32 distinct -> conflict-free column reads

  const int l = threadIdx.x;
  const int c = l & 15;   // sample within tile (C col / B col / A row)
  const int g = l >> 4;   // lane group
  const int s0 = blockIdx.x * 16;

  // ---- stage y tile: flat coalesced copy ----
  for (int i = l; i < 16 * WIN; i += 64) {
    const int s = i / WIN;
    ybuf[s][i - s * WIN] = y[s0 * WIN + i];
  }

  // ---- per-H constants: e = mt*4+r  ->  H = mt*16 + 4*g + r ----
  float w_in_r[16], b_in_r[16], ln_w_r[16], ln_b_r[16], decay_r[16];
#pragma unroll
  for (int mt = 0; mt < 4; ++mt) {
    const int hb4 = mt * 16 + g * 4;
    const float4 wi = *(const float4*)&w_in[hb4];
    const float4 bi = *(const float4*)&b_in[hb4];
    const float4 lw = *(const float4*)&ln_w[hb4];
    const float4 lb = *(const float4*)&ln_b[hb4];
    const float4 tp = *(const float4*)&tau_param[hb4];
#pragma unroll
    for (int r = 0; r < 4; ++r) {
      w_in_r[mt * 4 + r] = (&wi.x)[r];
      b_in_r[mt * 4 + r] = (&bi.x)[r];
      ln_w_r[mt * 4 + r] = (&lw.x)[r];
      ln_b_r[mt * 4 + r] = (&lb.x)[r];
      decay_r[mt * 4 + r] = 1.0f - DTC / softplus_fast((&tp.x)[r]);
    }
  }

  // ---- W_rec^T A-fragments: A[m=h_out][k=h_in]; lane row = c, k elems 4g+j ----
  f16x4 wrec[4][4];
#pragma unroll
  for (int mt = 0; mt < 4; ++mt)
#pragma unroll
    for (int kt = 0; kt < 4; ++kt)
#pragma unroll
      for (int j = 0; j < 4; ++j)
        wrec[mt][kt][j] = (_Float16)W_rec[(kt * 16 + g * 4 + j) * HH + mt * 16 + c];

  __syncthreads();  // ybuf ready

  // h state: hs[e] f32 (C layout), hb[kt] f16 B-fragments (same lane data)
  float hs[16] = {};
  f16x4 hb[4] = {};
  const float inv64 = 1.0f / 64.0f;

  // ================= Phase 1: 100-step scan (no LDS except 1 xt read) =================
  for (int t = 0; t < WIN; ++t) {
    const float xt = ybuf[c][t];
    float pre[16];
    float s1p[4], s2p[4];
#pragma unroll
    for (int mt = 0; mt < 4; ++mt) {
      f32x4 a = {0.f, 0.f, 0.f, 0.f};
#pragma unroll
      for (int kt = 0; kt < 4; ++kt)
        a = __builtin_amdgcn_mfma_f32_16x16x16f16(wrec[mt][kt], hb[kt], a, 0, 0, 0);
      float ps = 0.f, qs = 0.f;
#pragma unroll
      for (int r = 0; r < 4; ++r) {
        const int e = mt * 4 + r;
        const float p = a[r] + fmaf(xt, w_in_r[e], b_in_r[e]);
        pre[e] = p;
        ps += p;
        qs = fmaf(p, p, qs);
      }
      s1p[mt] = ps;
      s2p[mt] = qs;
    }
    float s1 = (s1p[0] + s1p[1]) + (s1p[2] + s1p[3]);
    float s2 = (s2p[0] + s2p[1]) + (s2p[2] + s2p[3]);
    s1 += __shfl_xor(s1, 16);
    s1 += __shfl_xor(s1, 32);
    s2 += __shfl_xor(s2, 16);
    s2 += __shfl_xor(s2, 32);
    const float mean = s1 * inv64;
    const float rstd = rsq_fast(fmaxf(fmaf(-mean, mean, s2 * inv64), 0.f) + LNEPS);
#pragma unroll
    for (int mt = 0; mt < 4; ++mt)
#pragma unroll
      for (int r = 0; r < 4; ++r) {
        const int e = mt * 4 + r;
        const float f = tanh_fast(fmaf((pre[e] - mean) * rstd, ln_w_r[e], ln_b_r[e]));
        const float hn = fminf(10.0f, fmaxf(-10.0f, fmaf(hs[e], decay_r[e], DTC * f)));
        hs[e] = hn;
        hb[mt][r] = (_Float16)hn;
      }
  }

  // ================= Phase 2: x^T = Wx0 @ h^T + bx0 =================
  float xs[16];
  f16x4 xfr[4];
#pragma unroll
  for (int mt = 0; mt < 4; ++mt) {
    f32x4 a = {0.f, 0.f, 0.f, 0.f};
#pragma unroll
    for (int kt = 0; kt < 4; ++kt) {
      const float4 w = *(const float4*)&Wx0[(mt * 16 + c) * HH + kt * 16 + 4 * g];
      f16x4 wf;
#pragma unroll
      for (int j = 0; j < 4; ++j) wf[j] = (_Float16)(&w.x)[j];
      a = __builtin_amdgcn_mfma_f32_16x16x16f16(wf, hb[kt], a, 0, 0, 0);
    }
    const float4 b4 = *(const float4*)&bx0[mt * 16 + 4 * g];
#pragma unroll
    for (int r = 0; r < 4; ++r) {
      xs[mt * 4 + r] = a[r] + (&b4.x)[r];
      xfr[mt][r] = (_Float16)xs[mt * 4 + r];
    }
  }

  // ---- y^T B-fragments (K padded 100 -> 112 with zeros) ----
  f16x4 yfr[7];
#pragma unroll
  for (int kt = 0; kt < 7; ++kt)
#pragma unroll
    for (int j = 0; j < 4; ++j) {
      const int t = kt * 16 + 4 * g + j;
      yfr[kt][j] = (t < WIN) ? (_Float16)ybuf[c][t] : (_Float16)0.0f;
    }

  // ================= Phase 3: ISTA, z^T = We_k@y^T + Wr_k@x^T + be =================
#pragma unroll 2
  for (int k = 0; k < KITER; ++k) {
    f32x4 acc[4];
#pragma unroll
    for (int mt = 0; mt < 4; ++mt) {
      f32x4 a = {0.f, 0.f, 0.f, 0.f};
      const int rowe = (k * AA + mt * 16 + c) * WIN;
#pragma unroll
      for (int kt = 0; kt < 7; ++kt) {
        f16x4 wf = {(_Float16)0.f, (_Float16)0.f, (_Float16)0.f, (_Float16)0.f};
        if (kt < 6 || g == 0) {
          const float4 w = *(const float4*)&We[rowe + kt * 16 + 4 * g];
#pragma unroll
          for (int j = 0; j < 4; ++j) wf[j] = (_Float16)(&w.x)[j];
        }
        a = __builtin_amdgcn_mfma_f32_16x16x16f16(wf, yfr[kt], a, 0, 0, 0);
      }
      const int rowr = (k * AA + mt * 16 + c) * AA;
#pragma unroll
      for (int kt = 0; kt < 4; ++kt) {
        const float4 w = *(const float4*)&Wr[rowr + kt * 16 + 4 * g];
        f16x4 wf;
#pragma unroll
        for (int j = 0; j < 4; ++j) wf[j] = (_Float16)(&w.x)[j];
        a = __builtin_amdgcn_mfma_f32_16x16x16f16(wf, xfr[kt], a, 0, 0, 0);
      }
      acc[mt] = a;
    }
#pragma unroll
    for (int mt = 0; mt < 4; ++mt) {
      const float4 be4 = *(const float4*)&be[k * AA + mt * 16 + 4 * g];
      const float4 th4 = *(const float4*)&thr[k * AA + mt * 16 + 4 * g];
#pragma unroll
      for (int r = 0; r < 4; ++r) {
        const float z = acc[mt][r] + (&be4.x)[r];
        const float lam = softplus_fast((&th4.x)[r]);
        const float v = fmaxf(fabsf(z) - lam, 0.0f);
        const float xv = copysignf(v, z);
        xs[mt * 4 + r] = xv;
        xfr[mt][r] = (_Float16)xv;
      }
    }
  }

  // ================= Phase 4: outputs =================
  float* __restrict__ outp = out;               // power (B, 4)
  float* __restrict__ outx = out + NB * NAPPC;  // x (B, 64)
#pragma unroll
  for (int mt = 0; mt < 4; ++mt) {
    float4 v;
#pragma unroll
    for (int r = 0; r < 4; ++r) (&v.x)[r] = xs[mt * 4 + r];
    *(float4*)&outx[(s0 + c) * AA + mt * 16 + 4 * g] = v;
  }

  // power: per p, partial over in-lane 16 a-values, then butterfly over g
  float P[4];
#pragma unroll
  for (int p = 0; p < NAPPC; ++p) {
    float acc = 0.f;
#pragma unroll
    for (int mt = 0; mt < 4; ++mt) {
      const float4 hw = *(const float4*)&head_W[p * AA + mt * 16 + 4 * g];
#pragma unroll
      for (int r = 0; r < 4; ++r) acc = fmaf(xs[mt * 4 + r], (&hw.x)[r], acc);
    }
    acc += __shfl_xor(acc, 16);
    acc += __shfl_xor(acc, 32);
    P[p] = acc + head_b[p];
  }
  if (g == 0) {
    float4 pv;
#pragma unroll
    for (int p = 0; p < 4; ++p) (&pv.x)[p] = P[p];
    *(float4*)&outp[(s0 + c) * NAPPC] = pv;
  }
}

extern "C" void kernel_launch(void* const* d_in, const int* in_sizes, int n_in,
                              void* d_out, int out_size, void* d_ws, size_t ws_size,
                              hipStream_t stream) {
  const float* y         = (const float*)d_in[0];
  const float* w_in      = (const float*)d_in[1];
  const float* b_in      = (const float*)d_in[2];
  const float* tau_param = (const float*)d_in[3];
  const float* W_rec     = (const float*)d_in[4];
  const float* ln_w      = (const float*)d_in[5];
  const float* ln_b      = (const float*)d_in[6];
  const float* Wx0       = (const float*)d_in[7];
  const float* bx0       = (const float*)d_in[8];
  const float* We        = (const float*)d_in[9];
  const float* be        = (const float*)d_in[10];
  const float* Wr        = (const float*)d_in[11];
  const float* thr       = (const float*)d_in[12];
  const float* head_W    = (const float*)d_in[13];
  const float* head_b    = (const float*)d_in[14];

  pinn_fused<<<dim3(NB / 16), dim3(64), 0, stream>>>(
      y, w_in, b_in, tau_param, W_rec, ln_w, ln_b, Wx0, bx0, We, be, Wr, thr,
      head_W, head_b, (float*)d_out);
}

// Round 4
// 135.661 us; speedup vs baseline: 2.2796x; 1.2559x over previous
//
#include <hip/hip_runtime.h>

// Fully-fused PINN-LISTA, transposed-MFMA formulation + prep-kernel prefold.
// Prep kernel (runs first, same stream):
//   - W' = centering(C=I-J/64) folded into W_rec^T, stored f16 in A-fragment order
//   - w_c = w_in - mean, b_c = b_in - mean (f32)  -> LN mean term vanishes
//   - decay = 1 - DT/softplus(tau), lam = softplus(thr) (f32)
//   - We (zero-padded K 100->112) and Wr cast to f16
// Main kernel: 1 wave = 16 samples; scan keeps h in MFMA-C/B-fragment registers
// (transposed product => C layout == next B layout, no LDS in the loop).
// Variance-only LN reduce (2 shfls), 5-op NaN-free tanh, pkrtz packing.

#define NB 32768
#define WIN 100
#define HH 64
#define AA 64
#define KITER 8
#define NAPPC 4
#define DTC 0.1f
#define LNEPS 1e-5f
#define K2E 2.8853900817779268f  // 2*log2(e)

// d_ws byte offsets
#define WS_WREC 0        // f16 [4][4][64][4]   = 8192 B
#define WS_WE   8192     // f16 [8][64][112]    = 114688 B
#define WS_WR   122880   // f16 [8][64][64]     = 65536 B
#define WS_WC   188416   // f32 [64]
#define WS_BC   188672   // f32 [64]
#define WS_DEC  188928   // f32 [64]
#define WS_LAM  189184   // f32 [8][64] -> ends 191232

typedef _Float16 f16x4 __attribute__((ext_vector_type(4)));
typedef __fp16 fp16x2 __attribute__((ext_vector_type(2)));
typedef float f32x4 __attribute__((ext_vector_type(4)));

union H4 { f16x4 v; fp16x2 h[2]; };

__device__ __forceinline__ float exp2_fast(float x) { return __builtin_amdgcn_exp2f(x); }
__device__ __forceinline__ float rcp_fast(float x) { return __builtin_amdgcn_rcpf(x); }
__device__ __forceinline__ float rsq_fast(float x) { return __builtin_amdgcn_rsqf(x); }
__device__ __forceinline__ float log2_fast(float x) { return __builtin_amdgcn_logf(x); }
__device__ __forceinline__ float med3(float x, float lo, float hi) {
  return __builtin_amdgcn_fmed3f(x, lo, hi);
}
__device__ __forceinline__ float softplus_fast(float x) {
  float ax = fabsf(x);
  float e = exp2_fast(-ax * 1.4426950408889634f);
  return fmaxf(x, 0.0f) + log2_fast(1.0f + e) * 0.6931471805599453f;
}
__device__ __forceinline__ f16x4 pack4(float a, float b, float c2, float d) {
  H4 t;
  t.h[0] = __builtin_amdgcn_cvt_pkrtz(a, b);
  t.h[1] = __builtin_amdgcn_cvt_pkrtz(c2, d);
  return t.v;
}

// ======================= prep kernel =======================
__global__ __launch_bounds__(256) void pinn_prep(
    const float* __restrict__ W_rec, const float* __restrict__ w_in,
    const float* __restrict__ b_in, const float* __restrict__ tau,
    const float* __restrict__ thr, const float* __restrict__ We,
    const float* __restrict__ Wr, char* __restrict__ ws) {
  _Float16* wrec16 = (_Float16*)(ws + WS_WREC);
  _Float16* we16 = (_Float16*)(ws + WS_WE);
  _Float16* wr16 = (_Float16*)(ws + WS_WR);
  float* wc = (float*)(ws + WS_WC);
  float* bc = (float*)(ws + WS_BC);
  float* dec = (float*)(ws + WS_DEC);
  float* lam = (float*)(ws + WS_LAM);
  const int tid = threadIdx.x, bid = blockIdx.x;
  if (bid == 0) {
    __shared__ float rm[64];
    if (tid < 64) {
      float s = 0.f;
      for (int m = 0; m < 64; ++m) s += W_rec[tid * 64 + m];
      rm[tid] = s * (1.f / 64.f);
    }
    __syncthreads();
    for (int idx = tid; idx < 4096; idx += 256) {
      const int j = idx & 3, l = (idx >> 2) & 63, kt = (idx >> 8) & 3, mt = idx >> 10;
      const int k_in = kt * 16 + ((l >> 4) << 2) + j, m = mt * 16 + (l & 15);
      wrec16[idx] = (_Float16)(W_rec[k_in * 64 + m] - rm[k_in]);
    }
    if (tid < 64) {
      float sw = 0.f, sb = 0.f;
      for (int i = 0; i < 64; ++i) { sw += w_in[i]; sb += b_in[i]; }
      wc[tid] = w_in[tid] - sw * (1.f / 64.f);
      bc[tid] = b_in[tid] - sb * (1.f / 64.f);
      dec[tid] = 1.f - DTC / softplus_fast(tau[tid]);
    }
    for (int i = tid; i < 512; i += 256) lam[i] = softplus_fast(thr[i]);
  } else {
    const int stride = (gridDim.x - 1) * 256;
    for (int i = (bid - 1) * 256 + tid; i < 57344 + 32768; i += stride) {
      if (i < 57344) {
        const int row = i / 112, t = i - row * 112;
        we16[i] = (t < WIN) ? (_Float16)We[row * WIN + t] : (_Float16)0.f;
      } else {
        const int j = i - 57344;
        wr16[j] = (_Float16)Wr[j];
      }
    }
  }
}

// ======================= main kernel =======================
__global__ __launch_bounds__(64, 2) void pinn_fused(
    const float* __restrict__ y, const float* __restrict__ ln_w,
    const float* __restrict__ ln_b, const float* __restrict__ Wx0,
    const float* __restrict__ bx0, const float* __restrict__ be,
    const float* __restrict__ head_W, const float* __restrict__ head_b,
    const char* __restrict__ ws, float* __restrict__ out) {
  __shared__ float ybuf[16][101];  // stride 101 -> conflict-free column reads

  const _Float16* wrec16 = (const _Float16*)(ws + WS_WREC);
  const _Float16* we16 = (const _Float16*)(ws + WS_WE);
  const _Float16* wr16 = (const _Float16*)(ws + WS_WR);
  const float* wcp = (const float*)(ws + WS_WC);
  const float* bcp = (const float*)(ws + WS_BC);
  const float* decp = (const float*)(ws + WS_DEC);
  const float* lamp = (const float*)(ws + WS_LAM);

  const int l = threadIdx.x;
  const int c = l & 15;  // sample (C col / B col / A row)
  const int g = l >> 4;  // lane group
  const int s0 = blockIdx.x * 16;

  // ---- stage y tile ----
  for (int i = l; i < 16 * WIN; i += 64) {
    const int s = i / WIN;
    ybuf[s][i - s * WIN] = y[s0 * WIN + i];
  }

  // ---- per-H constants: e = mt*4+r -> H = mt*16 + 4*g + r ----
  float wc_r[16], bc_r[16], lnwK[16], lnbK[16], dec_r[16];
#pragma unroll
  for (int mt = 0; mt < 4; ++mt) {
    const int hb4 = mt * 16 + g * 4;
    const float4 wi = *(const float4*)&wcp[hb4];
    const float4 bi = *(const float4*)&bcp[hb4];
    const float4 lw = *(const float4*)&ln_w[hb4];
    const float4 lb = *(const float4*)&ln_b[hb4];
    const float4 dc = *(const float4*)&decp[hb4];
#pragma unroll
    for (int r = 0; r < 4; ++r) {
      wc_r[mt * 4 + r] = (&wi.x)[r];
      bc_r[mt * 4 + r] = (&bi.x)[r];
      lnwK[mt * 4 + r] = (&lw.x)[r] * K2E;
      lnbK[mt * 4 + r] = (&lb.x)[r] * K2E;
      dec_r[mt * 4 + r] = (&dc.x)[r];
    }
  }

  // ---- centered W' A-fragments: one 8B load per (mt,kt) ----
  f16x4 wrec[4][4];
#pragma unroll
  for (int mt = 0; mt < 4; ++mt)
#pragma unroll
    for (int kt = 0; kt < 4; ++kt)
      wrec[mt][kt] = *(const f16x4*)&wrec16[((mt * 4 + kt) * 64 + l) * 4];

  __syncthreads();  // ybuf ready

  float hs[16] = {};
  f16x4 hb[4] = {};
  const float inv64 = 1.0f / 64.0f;

  // ================= Phase 1: 100-step scan =================
  float xt = ybuf[c][0];
  for (int t = 0; t < WIN; ++t) {
    const float xtn = ybuf[c][t + 1];  // col 100 in-bounds (padded), unused at t=99
    f32x4 acc[4];
#pragma unroll
    for (int mt = 0; mt < 4; ++mt) {
      f32x4 a;
#pragma unroll
      for (int r = 0; r < 4; ++r) a[r] = fmaf(xt, wc_r[mt * 4 + r], bc_r[mt * 4 + r]);
#pragma unroll
      for (int kt = 0; kt < 4; ++kt)
        a = __builtin_amdgcn_mfma_f32_16x16x16f16(wrec[mt][kt], hb[kt], a, 0, 0, 0);
      acc[mt] = a;
    }
    // variance-only LN reduce (d is centered by construction)
    float qp[4];
#pragma unroll
    for (int mt = 0; mt < 4; ++mt) {
      float q = acc[mt][0] * acc[mt][0];
      q = fmaf(acc[mt][1], acc[mt][1], q);
      q = fmaf(acc[mt][2], acc[mt][2], q);
      q = fmaf(acc[mt][3], acc[mt][3], q);
      qp[mt] = q;
    }
    float q = (qp[0] + qp[1]) + (qp[2] + qp[3]);
    q += __shfl_xor(q, 16);
    q += __shfl_xor(q, 32);
    const float rstd = rsq_fast(fmaf(q, inv64, LNEPS));
#pragma unroll
    for (int mt = 0; mt < 4; ++mt) {
      float hn[4];
#pragma unroll
      for (int r = 0; r < 4; ++r) {
        const int e = mt * 4 + r;
        const float u2 = fmaf(acc[mt][r] * rstd, lnwK[e], lnbK[e]);  // 2u*log2e
        const float tt = fmaf(-2.f, rcp_fast(exp2_fast(u2) + 1.f), 1.f);
        hn[r] = med3(fmaf(hs[e], dec_r[e], DTC * tt), -10.f, 10.f);
        hs[e] = hn[r];
      }
      hb[mt] = pack4(hn[0], hn[1], hn[2], hn[3]);
    }
    xt = xtn;
  }

  // ================= Phase 2: x^T = Wx0 @ h^T + bx0 =================
  float xs[16];
  f16x4 xfr[4];
#pragma unroll
  for (int mt = 0; mt < 4; ++mt) {
    const float4 b4 = *(const float4*)&bx0[mt * 16 + 4 * g];
    f32x4 a = {b4.x, b4.y, b4.z, b4.w};
#pragma unroll
    for (int kt = 0; kt < 4; ++kt) {
      const float4 w = *(const float4*)&Wx0[(mt * 16 + c) * HH + kt * 16 + 4 * g];
      a = __builtin_amdgcn_mfma_f32_16x16x16f16(pack4(w.x, w.y, w.z, w.w), hb[kt], a, 0, 0, 0);
    }
#pragma unroll
    for (int r = 0; r < 4; ++r) xs[mt * 4 + r] = a[r];
    xfr[mt] = pack4(a[0], a[1], a[2], a[3]);
  }

  // ---- y^T B-fragments (t >= 100 zero; We padded to 112 in ws) ----
  f16x4 yfr[7];
#pragma unroll
  for (int kt = 0; kt < 7; ++kt) {
    const int t0 = kt * 16 + 4 * g;
    if (t0 + 3 < WIN) {
      yfr[kt] = pack4(ybuf[c][t0], ybuf[c][t0 + 1], ybuf[c][t0 + 2], ybuf[c][t0 + 3]);
    } else {
      yfr[kt] = pack4(0.f, 0.f, 0.f, 0.f);
    }
  }

  // ================= Phase 3: ISTA =================
  for (int k = 0; k < KITER; ++k) {
    f32x4 acc[4];
#pragma unroll
    for (int mt = 0; mt < 4; ++mt) {
      const float4 be4 = *(const float4*)&be[k * AA + mt * 16 + 4 * g];
      f32x4 a = {be4.x, be4.y, be4.z, be4.w};
      const int rowe = (k * AA + mt * 16 + c) * 112;
#pragma unroll
      for (int kt = 0; kt < 7; ++kt) {
        const f16x4 wf = *(const f16x4*)&we16[rowe + kt * 16 + 4 * g];
        a = __builtin_amdgcn_mfma_f32_16x16x16f16(wf, yfr[kt], a, 0, 0, 0);
      }
      const int rowr = (k * AA + mt * 16 + c) * AA;
#pragma unroll
      for (int kt = 0; kt < 4; ++kt) {
        const f16x4 wf = *(const f16x4*)&wr16[rowr + kt * 16 + 4 * g];
        a = __builtin_amdgcn_mfma_f32_16x16x16f16(wf, xfr[kt], a, 0, 0, 0);
      }
      acc[mt] = a;
    }
#pragma unroll
    for (int mt = 0; mt < 4; ++mt) {
      const float4 lm4 = *(const float4*)&lamp[k * AA + mt * 16 + 4 * g];
      float xv[4];
#pragma unroll
      for (int r = 0; r < 4; ++r) {
        const float z = acc[mt][r];
        const float v = fmaxf(fabsf(z) - (&lm4.x)[r], 0.0f);
        xv[r] = copysignf(v, z);
        xs[mt * 4 + r] = xv[r];
      }
      xfr[mt] = pack4(xv[0], xv[1], xv[2], xv[3]);
    }
  }

  // ================= Phase 4: outputs =================
  float* __restrict__ outp = out;               // power (B, 4)
  float* __restrict__ outx = out + NB * NAPPC;  // x (B, 64)
#pragma unroll
  for (int mt = 0; mt < 4; ++mt) {
    float4 v;
#pragma unroll
    for (int r = 0; r < 4; ++r) (&v.x)[r] = xs[mt * 4 + r];
    *(float4*)&outx[(s0 + c) * AA + mt * 16 + 4 * g] = v;
  }

  float P[4];
#pragma unroll
  for (int p = 0; p < NAPPC; ++p) {
    float acc = 0.f;
#pragma unroll
    for (int mt = 0; mt < 4; ++mt) {
      const float4 hw = *(const float4*)&head_W[p * AA + mt * 16 + 4 * g];
#pragma unroll
      for (int r = 0; r < 4; ++r) acc = fmaf(xs[mt * 4 + r], (&hw.x)[r], acc);
    }
    acc += __shfl_xor(acc, 16);
    acc += __shfl_xor(acc, 32);
    P[p] = acc + head_b[p];
  }
  if (g == 0) {
    float4 pv;
#pragma unroll
    for (int p = 0; p < 4; ++p) (&pv.x)[p] = P[p];
    *(float4*)&outp[(s0 + c) * NAPPC] = pv;
  }
}

extern "C" void kernel_launch(void* const* d_in, const int* in_sizes, int n_in,
                              void* d_out, int out_size, void* d_ws, size_t ws_size,
                              hipStream_t stream) {
  const float* y         = (const float*)d_in[0];
  const float* w_in      = (const float*)d_in[1];
  const float* b_in      = (const float*)d_in[2];
  const float* tau_param = (const float*)d_in[3];
  const float* W_rec     = (const float*)d_in[4];
  const float* ln_w      = (const float*)d_in[5];
  const float* ln_b      = (const float*)d_in[6];
  const float* Wx0       = (const float*)d_in[7];
  const float* bx0       = (const float*)d_in[8];
  const float* be        = (const float*)d_in[10];
  const float* Wr        = (const float*)d_in[11];
  const float* thr       = (const float*)d_in[12];
  const float* head_W    = (const float*)d_in[13];
  const float* head_b    = (const float*)d_in[14];
  const float* We        = (const float*)d_in[9];

  pinn_prep<<<dim3(90), dim3(256), 0, stream>>>(
      W_rec, w_in, b_in, tau_param, thr, We, Wr, (char*)d_ws);
  pinn_fused<<<dim3(NB / 16), dim3(64), 0, stream>>>(
      y, ln_w, ln_b, Wx0, bx0, be, head_W, head_b, (const char*)d_ws,
      (float*)d_out);
}